// Round 11
// baseline (1076.266 us; speedup 1.0000x reference)
//
#include <hip/hip_runtime.h>
#include <math.h>

#define EPS 1e-6f

// ===== measurement round: two main-kernel variants in one launch =====
// Dispatch 1: paced-slicing (H1: traffic reduction via L2-resident window)
// Dispatch 2: plain, 2 quads/thread (H2: latency/MLP limit) — writes final out
// Dispatch 3: reduce (over dispatch-2 partials)

#define SLICE_SHIFT 17
#define NSLICE 16

typedef int v4i __attribute__((ext_vector_type(4)));

struct __attribute__((packed, aligned(4))) Vert3 { float x, y, z; };

__device__ __forceinline__ float edge_cos_v(
    float p0x,float p0y,float p0z, float p1x,float p1y,float p1z,
    float p2x,float p2y,float p2z, float p3x,float p3y,float p3z)
{
    float ax = p1x - p0x, ay = p1y - p0y, az = p1z - p0z;
    float bx = p2x - p0x, by = p2y - p0y, bz = p2z - p0z;
    float cx = p3x - p0x, cy = p3y - p0y, cz = p3z - p0z;

    float al2 = ax*ax + ay*ay + az*az;
    float al1 = sqrtf(al2 + EPS);

    float bl2 = bx*bx + by*by + bz*bz;
    float bl1 = sqrtf(bl2 + EPS);
    float ab  = ax*bx + ay*by + az*bz;
    float cos1 = ab / (al1 * bl1 + EPS);
    float sin1 = sqrtf(1.0f - cos1*cos1 + EPS);
    float t1   = ab / (al2 + EPS);
    float cb1x = bx - ax*t1, cb1y = by - ay*t1, cb1z = bz - az*t1;
    float cb1l = bl1 * sin1;

    float cl2 = cx*cx + cy*cy + cz*cz;
    float cl1 = sqrtf(cl2 + EPS);
    float ac  = ax*cx + ay*cy + az*cz;
    float cos2 = ac / (al1 * cl1 + EPS);
    float sin2 = sqrtf(1.0f - cos2*cos2 + EPS);
    float t2   = ac / (al2 + EPS);
    float cb2x = cx - ax*t2, cb2y = cy - ay*t2, cb2z = cz - az*t2;
    float cb2l = cl1 * sin2;

    float num = cb1x*cb2x + cb1y*cb2y + cb1z*cb2z;
    return num / (cb1l * cb2l + EPS);
}

// ---------- Variant A: paced temporal slicing (one quad/thread) ----------
__global__ __launch_bounds__(256) void sf_main_sliced(
    const Vert3* __restrict__ verts,
    const int* __restrict__ v0s, const int* __restrict__ v1s,
    const int* __restrict__ v2s, const int* __restrict__ v3s,
    float* __restrict__ cos_out, double* __restrict__ partials, int nquad)
{
    const int q      = blockIdx.x * blockDim.x + threadIdx.x;
    const bool valid = q < nquad;
    const int qq     = valid ? q : 0;

    v4i i0 = __builtin_nontemporal_load((const v4i*)v0s + qq);
    v4i i1 = __builtin_nontemporal_load((const v4i*)v1s + qq);
    v4i i2 = __builtin_nontemporal_load((const v4i*)v2s + qq);
    v4i i3 = __builtin_nontemporal_load((const v4i*)v3s + qq);

    int idx[16];
    idx[0]=i0.x;  idx[1]=i0.y;  idx[2]=i0.z;  idx[3]=i0.w;
    idx[4]=i1.x;  idx[5]=i1.y;  idx[6]=i1.z;  idx[7]=i1.w;
    idx[8]=i2.x;  idx[9]=i2.y;  idx[10]=i2.z; idx[11]=i2.w;
    idx[12]=i3.x; idx[13]=i3.y; idx[14]=i3.z; idx[15]=i3.w;

    float vx[16], vy[16], vz[16];

    #pragma unroll
    for (int s = 0; s < NSLICE; ++s) {
        #pragma unroll
        for (int r = 0; r < 16; ++r) {
            int sid = idx[r] >> SLICE_SHIFT;
            bool hit = (s == NSLICE - 1) ? (sid >= s) : (sid == s);
            if (hit) {
                Vert3 p = verts[idx[r]];
                vx[r] = p.x; vy[r] = p.y; vz[r] = p.z;
            }
        }
        asm volatile("s_waitcnt vmcnt(0)" ::: "memory");
        __syncthreads();
    }

    double acc = 0.0;
    if (valid) {
        float cres[4];
        #pragma unroll
        for (int e = 0; e < 4; ++e)
            cres[e] = edge_cos_v(vx[e],vy[e],vz[e], vx[4+e],vy[4+e],vz[4+e],
                                 vx[8+e],vy[8+e],vz[8+e], vx[12+e],vy[12+e],vz[12+e]);
        int base = q << 2;
        __builtin_nontemporal_store(cres[0], cos_out + base + 0);
        __builtin_nontemporal_store(cres[1], cos_out + base + 1);
        __builtin_nontemporal_store(cres[2], cos_out + base + 2);
        __builtin_nontemporal_store(cres[3], cos_out + base + 3);
        float d0=cres[0]+1.0f, d1=cres[1]+1.0f, d2=cres[2]+1.0f, d3=cres[3]+1.0f;
        acc = (double)(d0*d0)+(double)(d1*d1)+(double)(d2*d2)+(double)(d3*d3);
    }

    #pragma unroll
    for (int off = 32; off > 0; off >>= 1) acc += __shfl_down(acc, off, 64);
    __shared__ double smem[4];
    int wid = threadIdx.x >> 6, lane = threadIdx.x & 63;
    if (lane == 0) smem[wid] = acc;
    __syncthreads();
    if (threadIdx.x == 0)
        partials[blockIdx.x] = smem[0]+smem[1]+smem[2]+smem[3];
}

// ---------- Variant B: plain gathers, 2 independent quads/thread ----------
// Strided split (q and q+half) keeps every index load perfectly coalesced.
// 32 gathers in flight per thread -> 2x MLP vs R5.
__global__ __launch_bounds__(256) void sf_main_plain2(
    const Vert3* __restrict__ verts,
    const int* __restrict__ v0s, const int* __restrict__ v1s,
    const int* __restrict__ v2s, const int* __restrict__ v3s,
    float* __restrict__ cos_out, double* __restrict__ partials, int half)
{
    const int t = blockIdx.x * blockDim.x + threadIdx.x;
    double acc = 0.0;

    if (t < half) {
        const int qA = t, qB = t + half;

        v4i a0 = __builtin_nontemporal_load((const v4i*)v0s + qA);
        v4i a1 = __builtin_nontemporal_load((const v4i*)v1s + qA);
        v4i a2 = __builtin_nontemporal_load((const v4i*)v2s + qA);
        v4i a3 = __builtin_nontemporal_load((const v4i*)v3s + qA);
        v4i b0 = __builtin_nontemporal_load((const v4i*)v0s + qB);
        v4i b1 = __builtin_nontemporal_load((const v4i*)v1s + qB);
        v4i b2 = __builtin_nontemporal_load((const v4i*)v2s + qB);
        v4i b3 = __builtin_nontemporal_load((const v4i*)v3s + qB);

        // issue all 32 gathers before first use
        Vert3 pA0[4] = { verts[a0.x], verts[a0.y], verts[a0.z], verts[a0.w] };
        Vert3 pA1[4] = { verts[a1.x], verts[a1.y], verts[a1.z], verts[a1.w] };
        Vert3 pA2[4] = { verts[a2.x], verts[a2.y], verts[a2.z], verts[a2.w] };
        Vert3 pA3[4] = { verts[a3.x], verts[a3.y], verts[a3.z], verts[a3.w] };
        Vert3 pB0[4] = { verts[b0.x], verts[b0.y], verts[b0.z], verts[b0.w] };
        Vert3 pB1[4] = { verts[b1.x], verts[b1.y], verts[b1.z], verts[b1.w] };
        Vert3 pB2[4] = { verts[b2.x], verts[b2.y], verts[b2.z], verts[b2.w] };
        Vert3 pB3[4] = { verts[b3.x], verts[b3.y], verts[b3.z], verts[b3.w] };

        int baseA = qA << 2, baseB = qB << 2;
        #pragma unroll
        for (int e = 0; e < 4; ++e) {
            float cA = edge_cos_v(pA0[e].x,pA0[e].y,pA0[e].z, pA1[e].x,pA1[e].y,pA1[e].z,
                                  pA2[e].x,pA2[e].y,pA2[e].z, pA3[e].x,pA3[e].y,pA3[e].z);
            float cB = edge_cos_v(pB0[e].x,pB0[e].y,pB0[e].z, pB1[e].x,pB1[e].y,pB1[e].z,
                                  pB2[e].x,pB2[e].y,pB2[e].z, pB3[e].x,pB3[e].y,pB3[e].z);
            __builtin_nontemporal_store(cA, cos_out + baseA + e);
            __builtin_nontemporal_store(cB, cos_out + baseB + e);
            float dA = cA + 1.0f, dB = cB + 1.0f;
            acc += (double)(dA*dA) + (double)(dB*dB);
        }
    }

    #pragma unroll
    for (int off = 32; off > 0; off >>= 1) acc += __shfl_down(acc, off, 64);
    __shared__ double smem[4];
    int wid = threadIdx.x >> 6, lane = threadIdx.x & 63;
    if (lane == 0) smem[wid] = acc;
    __syncthreads();
    if (threadIdx.x == 0)
        partials[blockIdx.x] = smem[0]+smem[1]+smem[2]+smem[3];
}

__global__ __launch_bounds__(256) void soft_flatten_reduce(
    const double* __restrict__ partials, int n, float* __restrict__ out)
{
    double acc = 0.0;
    for (int i = threadIdx.x; i < n; i += 256) acc += partials[i];
    #pragma unroll
    for (int off = 32; off > 0; off >>= 1) acc += __shfl_down(acc, off, 64);
    __shared__ double smem[4];
    int wid = threadIdx.x >> 6, lane = threadIdx.x & 63;
    if (lane == 0) smem[wid] = acc;
    __syncthreads();
    if (threadIdx.x == 0)
        out[0] = (float)(smem[0]+smem[1]+smem[2]+smem[3]);
}

extern "C" void kernel_launch(void* const* d_in, const int* in_sizes, int n_in,
                              void* d_out, int out_size, void* d_ws, size_t ws_size,
                              hipStream_t stream) {
    const Vert3* verts = (const Vert3*)d_in[0];
    const int*   v0s   = (const int*)d_in[1];
    const int*   v1s   = (const int*)d_in[2];
    const int*   v2s   = (const int*)d_in[3];
    const int*   v3s   = (const int*)d_in[4];

    const int nE    = in_sizes[1];        // 6,000,000
    const int nquad = nE >> 2;            // 1,500,000
    const int half  = nquad >> 1;         // 750,000
    float* loss_out = (float*)d_out;
    float* cos_out  = (float*)d_out + 1;
    double* partials = (double*)d_ws;

    // Dispatch 1 (measurement): paced slicing. Its cos/partials writes are
    // overwritten by dispatch 2, which produces the final (validated) output.
    const int BLOCKS_A = (nquad + 255) / 256;   // 5860
    sf_main_sliced<<<BLOCKS_A, 256, 0, stream>>>(
        verts, v0s, v1s, v2s, v3s, cos_out, partials, nquad);

    // Dispatch 2 (measurement + final output): plain, 2 quads/thread.
    const int BLOCKS_B = (half + 255) / 256;    // 2930
    sf_main_plain2<<<BLOCKS_B, 256, 0, stream>>>(
        verts, v0s, v1s, v2s, v3s, cos_out, partials, half);

    soft_flatten_reduce<<<1, 256, 0, stream>>>(partials, BLOCKS_B, loss_out);
}